// Round 3
// baseline (720.369 us; speedup 1.0000x reference)
//
#include <hip/hip_runtime.h>

#define C_DIM 256
#define S_SEG 16

typedef __attribute__((ext_vector_type(8))) short bf16x8;
typedef __attribute__((ext_vector_type(4))) float f32x4;

__device__ __forceinline__ short f2bf(float f) {
    unsigned u = __builtin_bit_cast(unsigned, f);
    u += 0x7FFF + ((u >> 16) & 1);   // round-to-nearest-even
    return (short)(u >> 16);
}

// decode o (int64 or int32 layout) -> value i. If int64, word 1 (= high word of
// o[0]) is 0; if int32, word 1 is o[1] >= 2 (strictly increasing, o[0] >= 1).
__device__ __forceinline__ int o_get(const int* __restrict__ o_raw, int i) {
    return (o_raw[1] == 0) ? o_raw[2 * i] : o_raw[i];
}

// ---------------- Kernel 1: per-segment column sums + bf16 A-fragment copy ----
// grid 1024 blocks x 256 threads; block handles 256 rows. Thread t:
// rsub = t>>6 (row quarter of 64 rows), cg = t&63 (float4 column group).
// Besides segment sums, emits xb: bf16 copy of x in MFMA A-fragment order
//   elem (row,k): [tile=row>>4][ktg=k>>5][lane=((k>>3)&3)*16 + (row&15)][j=k&7]
// so k3 can load A fragments with one lane-linear 16B global load, no LDS.
__global__ __launch_bounds__(256) void k1_segsum_conv(const float* __restrict__ x,
                                                      const int* __restrict__ o_raw,
                                                      float* __restrict__ sums,
                                                      short* __restrict__ xb) {
    __shared__ int o_s[S_SEG];
    __shared__ float4 partv[256];
    __shared__ int pseg[256];
    int t = threadIdx.x;
    if (t < S_SEG) o_s[t] = o_get(o_raw, t);
    __syncthreads();

    int rsub = t >> 6, cg = t & 63;
    int ktg = cg >> 3, q = (cg >> 1) & 3, j0 = (cg & 1) * 4;
    int row0 = blockIdx.x * 256 + rsub * 64;
    const float4* xv = (const float4*)x;

    int cur = 0;
#pragma unroll
    for (int j = 0; j < S_SEG; ++j) cur += (row0 >= o_s[j]);
    int next = o_s[cur];

    float4 acc = make_float4(0.f, 0.f, 0.f, 0.f);
    for (int i = 0; i < 64; ++i) {
        int row = row0 + i;
        if (row >= next) {  // rare: segment boundary inside this thread's rows
            atomicAdd(&sums[cur * C_DIM + cg * 4 + 0], acc.x);
            atomicAdd(&sums[cur * C_DIM + cg * 4 + 1], acc.y);
            atomicAdd(&sums[cur * C_DIM + cg * 4 + 2], acc.z);
            atomicAdd(&sums[cur * C_DIM + cg * 4 + 3], acc.w);
            acc = make_float4(0.f, 0.f, 0.f, 0.f);
            do { cur++; next = o_s[cur]; } while (row >= next);
        }
        float4 v = xv[row * 64 + cg];
        acc.x += v.x; acc.y += v.y; acc.z += v.z; acc.w += v.w;
        // bf16 fragment-layout store: 4 bf16 = 8 B
        unsigned lo = (unsigned)(unsigned short)f2bf(v.x) |
                      ((unsigned)(unsigned short)f2bf(v.y) << 16);
        unsigned hi = (unsigned)(unsigned short)f2bf(v.z) |
                      ((unsigned)(unsigned short)f2bf(v.w) << 16);
        long off = ((long)((row >> 4) * 8 + ktg) * 64 + q * 16 + (row & 15)) * 8 + j0;
        *(uint2*)&xb[off] = make_uint2(lo, hi);
    }
    partv[t] = acc;
    pseg[t] = cur;
    __syncthreads();

    if (t < 64) {  // merge the 4 row-quarters per column group (segs non-decreasing)
        float4 a = partv[t];
        int s = pseg[t];
        for (int i = 1; i < 4; ++i) {
            int idx = i * 64 + t;
            int s2 = pseg[idx];
            float4 a2 = partv[idx];
            if (s2 == s) {
                a.x += a2.x; a.y += a2.y; a.z += a2.z; a.w += a2.w;
            } else {
                atomicAdd(&sums[s * C_DIM + t * 4 + 0], a.x);
                atomicAdd(&sums[s * C_DIM + t * 4 + 1], a.y);
                atomicAdd(&sums[s * C_DIM + t * 4 + 2], a.z);
                atomicAdd(&sums[s * C_DIM + t * 4 + 3], a.w);
                s = s2; a = a2;
            }
        }
        atomicAdd(&sums[s * C_DIM + t * 4 + 0], a.x);
        atomicAdd(&sums[s * C_DIM + t * 4 + 1], a.y);
        atomicAdd(&sums[s * C_DIM + t * 4 + 2], a.z);
        atomicAdd(&sums[s * C_DIM + t * 4 + 3], a.w);
    }
}

// ---------------- Kernel 2: tiny per-segment math + W1s bf16 fragment-layout conversion
__global__ __launch_bounds__(256) void k2_small(const float* __restrict__ sums,
                                                const int* __restrict__ o_raw,
                                                const float* __restrict__ W2,
                                                const float* __restrict__ b2,
                                                const float* __restrict__ W1,
                                                const float* __restrict__ b1,
                                                const float* __restrict__ gamma,
                                                const float* __restrict__ beta,
                                                const float* __restrict__ rmean,
                                                const float* __restrict__ rvar,
                                                float* __restrict__ Cseg,
                                                short* __restrict__ W1s) {
    int t = threadIdx.x;
    int blk = blockIdx.x;
    if (blk < S_SEG) {
        __shared__ float mean_s[C_DIM];
        __shared__ float h_s[C_DIM];
        int s = blk;
        int lo = (s == 0) ? 0 : o_get(o_raw, s - 1);
        float inv = 1.0f / (float)(o_get(o_raw, s) - lo);
        mean_s[t] = sums[s * C_DIM + t] * inv;
        __syncthreads();
        float acc = b2[t];
#pragma unroll 4
        for (int k = 0; k < C_DIM; ++k) acc = fmaf(mean_s[k], W2[k * C_DIM + t], acc);
        h_s[t] = fmaxf(acc, 0.0f);
        __syncthreads();
        float acc2 = 0.f;
#pragma unroll 4
        for (int k = 0; k < C_DIM; ++k) acc2 = fmaf(h_s[k], W1[(C_DIM + k) * C_DIM + t], acc2);
        float sc = gamma[t] * rsqrtf(rvar[t] + 1e-5f);
        Cseg[s * C_DIM + t] = (b1[t] + acc2 - rmean[t]) * sc + beta[t];
    } else {
        // W1s[k][c] = bf16(W1[k][c]*scale[c]) in MFMA B-fragment order:
        // elem (k,c): ktg=k>>5, q=(k>>3)&3, j=k&7, nsub=c>>4, r=c&15
        // off = ((ktg*16+nsub)*64 + q*16 + r)*8 + j
        int base = (blk - S_SEG) * 8192;  // 8 blocks * 8192 = 65536 elements
        for (int i = 0; i < 32; ++i) {
            int idx = base + i * 256 + t;
            int k = idx >> 8, c = idx & 255;
            float sc = gamma[c] * rsqrtf(rvar[c] + 1e-5f);
            float v = W1[k * C_DIM + c] * sc;
            int ktg = k >> 5, q = (k >> 3) & 3, j = k & 7, nsub = c >> 4, r = c & 15;
            int off = ((ktg * 16 + nsub) * 64 + q * 16 + r) * 8 + j;
            W1s[off] = f2bf(v);
        }
    }
}

// ---------------- Kernel 3: out = relu(xb @ W1s + Cseg[seg(row)]) -------------
// grid 4096 blocks x 256 threads (4 waves). Block: 64 rows x 256 cols.
// A and B are both pre-laid-out in MFMA fragment order in global memory
// (xb hot in L3 from k1, W1s hot from k2) -> no LDS staging, no barriers in
// the K-loop, lane-linear 16B loads only. Reverse tile order so the freshest
// xb tiles (written last by k1) are read first.
__global__ __launch_bounds__(256) void k3_gemm(const short* __restrict__ xb,
                                               const short* __restrict__ W1s,
                                               const float* __restrict__ Cseg,
                                               const int* __restrict__ o_raw,
                                               float* __restrict__ out) {
    __shared__ int o_s[S_SEG];
    int t = threadIdx.x;
    int wave = t >> 6, lane = t & 63;
    int q = lane >> 4, r = lane & 15;
    int m0 = (int)(gridDim.x - 1 - blockIdx.x) * 64;  // reverse tile order
    int tile0 = m0 >> 4;

    if (t < S_SEG) o_s[t] = o_get(o_raw, t);
    __syncthreads();

    f32x4 acc[4][4];
#pragma unroll
    for (int mt = 0; mt < 4; ++mt)
#pragma unroll
        for (int nt = 0; nt < 4; ++nt)
            acc[mt][nt] = (f32x4){0.f, 0.f, 0.f, 0.f};

    const bf16x8* A = (const bf16x8*)xb;
    const bf16x8* B = (const bf16x8*)W1s;

#pragma unroll
    for (int ktg = 0; ktg < 8; ++ktg) {
        bf16x8 a[4], b[4];
#pragma unroll
        for (int mt = 0; mt < 4; ++mt)
            a[mt] = A[((long)(tile0 + mt) * 8 + ktg) * 64 + lane];
#pragma unroll
        for (int nt = 0; nt < 4; ++nt)
            b[nt] = B[(ktg * 16 + wave * 4 + nt) * 64 + lane];
#pragma unroll
        for (int mt = 0; mt < 4; ++mt)
#pragma unroll
            for (int nt = 0; nt < 4; ++nt)
                acc[mt][nt] = __builtin_amdgcn_mfma_f32_16x16x32_bf16(a[mt], b[nt], acc[mt][nt], 0, 0, 0);
    }

    // epilogue: D[row=q*4+i][col=r]; Cseg row is L1-resident after first touch
#pragma unroll
    for (int mt = 0; mt < 4; ++mt) {
#pragma unroll
        for (int i = 0; i < 4; ++i) {
            int row = m0 + mt * 16 + q * 4 + i;
            int s = 0;
#pragma unroll
            for (int j = 0; j < S_SEG; ++j) s += (row >= o_s[j]);
#pragma unroll
            for (int nt = 0; nt < 4; ++nt) {
                int col = wave * 64 + nt * 16 + r;
                float v = acc[mt][nt][i] + Cseg[s * C_DIM + col];
                __builtin_nontemporal_store(fmaxf(v, 0.0f), &out[(long)row * C_DIM + col]);
            }
        }
    }
}

extern "C" void kernel_launch(void* const* d_in, const int* in_sizes, int n_in,
                              void* d_out, int out_size, void* d_ws, size_t ws_size,
                              hipStream_t stream) {
    const float* x     = (const float*)d_in[0];
    const int*   o     = (const int*)d_in[1];
    const float* W2    = (const float*)d_in[2];
    const float* b2    = (const float*)d_in[3];
    const float* W1    = (const float*)d_in[4];
    const float* b1    = (const float*)d_in[5];
    const float* gamma = (const float*)d_in[6];
    const float* beta  = (const float*)d_in[7];
    const float* rmean = (const float*)d_in[8];
    const float* rvar  = (const float*)d_in[9];
    float* out = (float*)d_out;

    // workspace layout
    float* sums = (float*)d_ws;                           // 16 KB
    float* Cseg = (float*)((char*)d_ws + 16384);          // 16 KB
    short* W1s  = (short*)((char*)d_ws + 65536);          // 128 KB
    short* xb   = (short*)((char*)d_ws + (2u << 20));     // 128 MiB bf16 copy of x

    hipMemsetAsync(d_ws, 0, 16384, stream);  // zero sums
    k1_segsum_conv<<<1024, 256, 0, stream>>>(x, o, sums, xb);
    k2_small<<<24, 256, 0, stream>>>(sums, o, W2, b2, W1, b1, gamma, beta, rmean, rvar, Cseg, W1s);
    k3_gemm<<<4096, 256, 0, stream>>>(xb, W1s, Cseg, o, out);
}